// Round 1
// baseline (1188.649 us; speedup 1.0000x reference)
//
#include <hip/hip_runtime.h>
#include <hip/hip_bf16.h>

#define FHH 64
#define FWW 64
#define CIN 256
#define NB 4
#define NA 9
#define NANCH (FHH*FWW*NA)   // 36864
#define NPOS (FHH*FWW)       // 4096
#define OC_TOTAL 45
#define GOC 15               // oc per conv block group
#define TS 16                // spatial tile
#define CC 32                // input-channel chunk
#define MAXROIS 32
#define ROI 7
#define NEGV -1e30f

// ---------------- Conv: cls(9) + loc(36) heads, SAME 3x3 ----------------
// grid: b(4) x tiles(16) x groups(3) = 192 blocks, 256 threads
__global__ __launch_bounds__(256) void conv_kernel(
    const float* __restrict__ feat,    // [4,256,64,64]
    const float* __restrict__ wcls,    // [9,256,3,3]
    const float* __restrict__ wloc,    // [36,256,3,3]
    float* __restrict__ conv_out)      // [4,4096,45]  (raw, pre-sigmoid)
{
    __shared__ float lds[CC][18][18];
    int blk = blockIdx.x;
    int g    = blk % 3;
    int tile = (blk / 3) % 16;
    int b    = blk / 48;
    int ty0 = (tile >> 2) * TS;
    int tx0 = (tile & 3) * TS;
    int ly = threadIdx.x / TS;
    int lx = threadIdx.x % TS;

    float acc[GOC];
#pragma unroll
    for (int k = 0; k < GOC; ++k) acc[k] = 0.f;

    int ocbase = g * GOC;
    const float* wbase[GOC];
#pragma unroll
    for (int k = 0; k < GOC; ++k) {
        int oc = ocbase + k;
        wbase[k] = (oc < NA) ? (wcls + (size_t)oc * CIN * 9)
                             : (wloc + (size_t)(oc - NA) * CIN * 9);
    }

    for (int c0 = 0; c0 < CIN; c0 += CC) {
        __syncthreads();
        for (int idx = threadIdx.x; idx < CC * 18 * 18; idx += 256) {
            int c = idx / 324;
            int r = idx - c * 324;
            int y = r / 18;
            int x = r - y * 18;
            int gy = ty0 + y - 1;
            int gx = tx0 + x - 1;
            float v = 0.f;
            if (gy >= 0 && gy < FHH && gx >= 0 && gx < FWW)
                v = feat[((size_t)(b * CIN + c0 + c) * FHH + gy) * FWW + gx];
            lds[c][y][x] = v;
        }
        __syncthreads();
        for (int c = 0; c < CC; ++c) {
            int woff = (c0 + c) * 9;
#pragma unroll
            for (int dy = 0; dy < 3; ++dy) {
#pragma unroll
                for (int dx = 0; dx < 3; ++dx) {
                    float f = lds[c][ly + dy][lx + dx];
#pragma unroll
                    for (int k = 0; k < GOC; ++k) {
                        acc[k] += f * wbase[k][woff + dy * 3 + dx];
                    }
                }
            }
        }
    }

    int pos = (ty0 + ly) * FWW + (tx0 + lx);
    float* outp = conv_out + ((size_t)b * NPOS + pos) * OC_TOTAL + ocbase;
#pragma unroll
    for (int k = 0; k < GOC; ++k) outp[k] = acc[k];
}

// ---------------- Decode + clip + valid + score ----------------
__global__ __launch_bounds__(256) void decode_kernel(
    const float* __restrict__ conv_out,   // [4,4096,45]
    const float* __restrict__ anchors,    // [36864,4]
    const int* __restrict__ stridep,
    float* __restrict__ boxes,            // [4,36864,4]
    float* __restrict__ scores)           // [4,36864]  (-1 if invalid)
{
    int t = blockIdx.x * 256 + threadIdx.x;   // exactly 4*36864
    int b = t / NANCH;
    int n = t - b * NANCH;
    int pos = n / NA;
    int a = n - pos * NA;
    const float* co = conv_out + ((size_t)b * NPOS + pos) * OC_TOTAL;
    float cls = co[a];
    float sig = 1.f / (1.f + expf(-cls));
    float l0 = co[NA + a * 4 + 0];
    float l1 = co[NA + a * 4 + 1];
    float l2 = co[NA + a * 4 + 2];
    float l3 = co[NA + a * 4 + 3];
    const float* an = anchors + (size_t)n * 4;
    float ax1 = an[0], ay1 = an[1], ax2 = an[2], ay2 = an[3];
    float aw = ax2 - ax1, ah = ay2 - ay1;
    float acx = ax1 + 0.5f * aw, acy = ay1 + 0.5f * ah;
    float cx = acx + l0 * aw;
    float cy = acy + l1 * ah;
    float w = aw * expf(l2);
    float h = ah * expf(l3);
    float x1 = cx - 0.5f * w, y1 = cy - 0.5f * h;
    float x2 = cx + 0.5f * w, y2 = cy + 0.5f * h;
    x1 = fminf(fmaxf(x1, 0.f), 512.f);
    y1 = fminf(fmaxf(y1, 0.f), 512.f);
    x2 = fminf(fmaxf(x2, 0.f), 512.f);
    y2 = fminf(fmaxf(y2, 0.f), 512.f);
    int stride = stridep[0];
    float msz = 2.f * (float)stride;
    bool valid = (sig > 0.5f) && ((x2 - x1) >= msz) && ((y2 - y1) >= msz);
    float* bp = boxes + (size_t)t * 4;
    bp[0] = x1; bp[1] = y1; bp[2] = x2; bp[3] = y2;
    scores[t] = valid ? sig : -1.0f;
}

// ---------------- Greedy NMS (32 rounds) + outputs ----------------
// grid: 4 blocks (one per batch), 1024 threads
__global__ __launch_bounds__(1024) void nms_kernel(
    const float* __restrict__ boxes,   // [4,36864,4]
    const float* __restrict__ scores,  // [4,36864]
    const int* __restrict__ stridep,
    float* __restrict__ d_out,         // eval_boxes at 0, ok at 640
    int* __restrict__ ifb,             // [128][4] int feature boxes
    int* __restrict__ iok)             // [128]
{
    __shared__ float s[NANCH];
    __shared__ float red_s[16];
    __shared__ int   red_i[16];
    __shared__ int   picks_sh[MAXROIS];
    __shared__ float pscore_sh[MAXROIS];
    __shared__ float curbox[4];
    __shared__ int   cur_i_sh;
    __shared__ float cur_s_sh;

    int b = blockIdx.x;
    const float* Bb = boxes + (size_t)b * NANCH * 4;
    const float* Sb = scores + (size_t)b * NANCH;

    for (int j = threadIdx.x; j < NANCH; j += 1024) s[j] = Sb[j];
    __syncthreads();

    int lane = threadIdx.x & 63;
    int wave = threadIdx.x >> 6;

    for (int round = 0; round < MAXROIS; ++round) {
        // local argmax (each thread owns j = tid + k*1024; 36 entries)
        float bs = -2.f;
        int bi = 0x7fffffff;
        for (int j = threadIdx.x; j < NANCH; j += 1024) {
            float v = s[j];
            if (v > bs || (v == bs && j < bi)) { bs = v; bi = j; }
        }
        // wave reduce
#pragma unroll
        for (int off = 32; off >= 1; off >>= 1) {
            float os = __shfl_down(bs, off);
            int   oi = __shfl_down(bi, off);
            if (os > bs || (os == bs && oi < bi)) { bs = os; bi = oi; }
        }
        if (lane == 0) { red_s[wave] = bs; red_i[wave] = bi; }
        __syncthreads();
        if (threadIdx.x == 0) {
            float fs = red_s[0]; int fi = red_i[0];
#pragma unroll
            for (int w2 = 1; w2 < 16; ++w2) {
                float os = red_s[w2]; int oi = red_i[w2];
                if (os > fs || (os == fs && oi < fi)) { fs = os; fi = oi; }
            }
            cur_i_sh = fi;
            cur_s_sh = fs;
            picks_sh[round] = fi;
            pscore_sh[round] = fs;
            curbox[0] = Bb[(size_t)fi * 4 + 0];
            curbox[1] = Bb[(size_t)fi * 4 + 1];
            curbox[2] = Bb[(size_t)fi * 4 + 2];
            curbox[3] = Bb[(size_t)fi * 4 + 3];
        }
        __syncthreads();
        float cs = cur_s_sh;
        if (cs > 0.f) {
            float px1 = curbox[0], py1 = curbox[1], px2 = curbox[2], py2 = curbox[3];
            float parea = (px2 - px1) * (py2 - py1);
            for (int j = threadIdx.x; j < NANCH; j += 1024) {
                float v = s[j];
                if (v > 0.f) {
                    const float* bb = Bb + (size_t)j * 4;
                    float bx1 = bb[0], by1 = bb[1], bx2 = bb[2], by2 = bb[3];
                    float xx1 = fmaxf(px1, bx1), yy1 = fmaxf(py1, by1);
                    float xx2 = fminf(px2, bx2), yy2 = fminf(py2, by2);
                    float inter = fmaxf(xx2 - xx1, 0.f) * fmaxf(yy2 - yy1, 0.f);
                    float a2 = (bx2 - bx1) * (by2 - by1);
                    float iou = inter / (parea + a2 - inter + 1e-9f);
                    if (iou > 0.3f) s[j] = -1.f;
                }
            }
        }
        __syncthreads();
    }

    // outputs
    if (threadIdx.x < MAXROIS) {
        int i = threadIdx.x;
        int idx = picks_sh[i];
        float sc = pscore_sh[i];
        bool okv = sc > 0.f;
        const float* bb = Bb + (size_t)idx * 4;
        float x1 = bb[0], y1 = bb[1], x2 = bb[2], y2 = bb[3];
        float* eb = d_out + ((size_t)b * MAXROIS + i) * 5;
        eb[0] = okv ? x1 : 0.f;
        eb[1] = okv ? y1 : 0.f;
        eb[2] = okv ? x2 : 0.f;
        eb[3] = okv ? y2 : 0.f;
        eb[4] = okv ? sc : 0.f;
        d_out[NB * MAXROIS * 5 + b * MAXROIS + i] = okv ? 1.f : 0.f;
        int st = stridep[0];
        int ib0 = ((int)x1) / st;
        int ib1 = ((int)y1) / st;
        int ib2 = ((int)x2) / st;
        int ib3 = ((int)y2) / st;
        int fx1 = min(max(ib0, 0), FWW - 1);
        int fy1 = min(max(ib1, 0), FHH - 1);
        int fx2 = min(max(ib2, fx1 + 1), FWW);
        int fy2 = min(max(ib3, fy1 + 1), FHH);
        int r = b * MAXROIS + i;
        ifb[r * 4 + 0] = fx1;
        ifb[r * 4 + 1] = fy1;
        ifb[r * 4 + 2] = fx2;
        ifb[r * 4 + 3] = fy2;
        iok[r] = okv ? 1 : 0;
    }
}

// ---------------- Adaptive max-pool ROI extraction ----------------
// grid: 128 blocks (one per roi), 256 threads (one per channel)
__global__ __launch_bounds__(256) void roi_kernel(
    const float* __restrict__ feat,   // [4,256,64,64]
    const int* __restrict__ ifb,      // [128][4]
    const int* __restrict__ iok,      // [128]
    float* __restrict__ out_rois)     // [128,256,7,7]
{
    int r = blockIdx.x;
    int b = r >> 5;
    int c = threadIdx.x;
    float* outp = out_rois + ((size_t)r * CIN + c) * (ROI * ROI);
    if (!iok[r]) {
#pragma unroll
        for (int k = 0; k < ROI * ROI; ++k) outp[k] = 0.f;
        return;
    }
    int x1 = ifb[r * 4 + 0];
    int y1 = ifb[r * 4 + 1];
    int x2 = ifb[r * 4 + 2];
    int y2 = ifb[r * 4 + 3];
    int h = y2 - y1;
    int w = x2 - x1;
    const float* F = feat + (size_t)(b * CIN + c) * NPOS;
#pragma unroll
    for (int i = 0; i < ROI; ++i) {
        int rs = y1 + (i * h) / ROI;
        int re = y1 + ((i + 1) * h + ROI - 1) / ROI;
#pragma unroll
        for (int j = 0; j < ROI; ++j) {
            int csx = x1 + (j * w) / ROI;
            int cex = x1 + ((j + 1) * w + ROI - 1) / ROI;
            float m = NEGV;
            for (int y = rs; y < re; ++y) {
                const float* row = F + y * FWW;
                for (int x = csx; x < cex; ++x) m = fmaxf(m, row[x]);
            }
            outp[i * ROI + j] = m;
        }
    }
}

extern "C" void kernel_launch(void* const* d_in, const int* in_sizes, int n_in,
                              void* d_out, int out_size, void* d_ws, size_t ws_size,
                              hipStream_t stream) {
    const float* feat    = (const float*)d_in[0];
    const float* anchors = (const float*)d_in[1];
    const float* wcls    = (const float*)d_in[2];
    const float* wloc    = (const float*)d_in[3];
    const int*   stridep = (const int*)d_in[4];
    float* out = (float*)d_out;
    float* ws  = (float*)d_ws;

    float* conv_out = ws;                         // 4*4096*45   = 737280
    float* boxes    = ws + 737280;                // 4*36864*4   = 589824
    float* scores   = ws + 737280 + 589824;       // 4*36864     = 147456
    int*   ifb      = (int*)(ws + 1474560);       // 128*4
    int*   iok      = ifb + 512;                  // 128

    conv_kernel<<<192, 256, 0, stream>>>(feat, wcls, wloc, conv_out);
    decode_kernel<<<(NB * NANCH) / 256, 256, 0, stream>>>(conv_out, anchors, stridep, boxes, scores);
    nms_kernel<<<NB, 1024, 0, stream>>>(boxes, scores, stridep, out, ifb, iok);
    roi_kernel<<<NB * MAXROIS, 256, 0, stream>>>(feat, ifb, iok, out + NB * MAXROIS * 5 + NB * MAXROIS);
}

// Round 2
// 1040.819 us; speedup vs baseline: 1.1420x; 1.1420x over previous
//
#include <hip/hip_runtime.h>
#include <hip/hip_bf16.h>

#define FHH 64
#define FWW 64
#define CIN 256
#define NB 4
#define NA 9
#define NANCH 36864
#define NPOS 4096
#define OC_TOTAL 45
#define MAXROIS 32
#define ROI 7
#define NEGV -1e30f
#define CC 32
#define NCHUNK 576   // NANCH / 64

// ---------------- Conv v3: 16x16 pos tile, 2x2 pos x 4 oc per thread ----------------
// grid: b(4) x tiles(16) x ocg(3) x nkg, 256 threads
__global__ __launch_bounds__(256) void conv_kernel(
    const float* __restrict__ feat,    // [4,256,64,64]
    const float* __restrict__ wcls,    // [9,256,3,3]
    const float* __restrict__ wloc,    // [36,256,3,3]
    float* __restrict__ partial,       // [nkg][4,4096,45]
    int nkg, int cpk)                  // cpk = 256/nkg channels per block
{
    __shared__ float flds[CC][18][18];     // 41472 B
    __shared__ float wlds[CC][9][16];      // 18432 B

    int blk = blockIdx.x;
    int kg   = blk % nkg;
    int g    = (blk / nkg) % 3;
    int tile = (blk / (nkg * 3)) % 16;
    int b    = blk / (nkg * 48);
    int ty0 = (tile >> 2) * 16;
    int tx0 = (tile & 3) * 16;

    int pb = threadIdx.x & 63;     // position block 0..63 (8x8 grid of 2x2)
    int q  = threadIdx.x >> 6;     // oc quad 0..3 (wave-uniform!)
    int ry0 = (pb >> 3) * 2;       // within-tile row of first output
    int rx0 = (pb & 7) * 2;

    int ocbase = g * 15;
    int cbase  = kg * cpk;

    float acc[2][2][4];
#pragma unroll
    for (int py = 0; py < 2; ++py)
#pragma unroll
        for (int px = 0; px < 2; ++px)
#pragma unroll
            for (int o = 0; o < 4; ++o) acc[py][px][o] = 0.f;

    for (int c0 = 0; c0 < cpk; c0 += CC) {
        __syncthreads();
        // stage feature tile 18x18 x CC
        for (int idx = threadIdx.x; idx < CC * 324; idx += 256) {
            int c = idx / 324;
            int r = idx - c * 324;
            int y = r / 18;
            int x = r - y * 18;
            int gy = ty0 + y - 1;
            int gx = tx0 + x - 1;
            float v = 0.f;
            if ((unsigned)gy < FHH && (unsigned)gx < FWW)
                v = feat[((size_t)(b * CIN + cbase + c0 + c) * FHH + gy) * FWW + gx];
            flds[c][y][x] = v;
        }
        // stage weights [c][tap][oc16]
        for (int idx = threadIdx.x; idx < CC * 144; idx += 256) {
            int o   = idx & 15;
            int tap = (idx >> 4) % 9;
            int c   = idx / 144;
            float v = 0.f;
            if (o < 15) {
                int oc = ocbase + o;
                v = (oc < NA)
                    ? wcls[((size_t)oc * CIN + cbase + c0 + c) * 9 + tap]
                    : wloc[((size_t)(oc - NA) * CIN + cbase + c0 + c) * 9 + tap];
            }
            wlds[c][tap][o] = v;
        }
        __syncthreads();

        for (int c = 0; c < CC; ++c) {
            float f[4][4];
#pragma unroll
            for (int r = 0; r < 4; ++r) {
                float2 a0 = *(const float2*)&flds[c][ry0 + r][rx0];
                float2 a1 = *(const float2*)&flds[c][ry0 + r][rx0 + 2];
                f[r][0] = a0.x; f[r][1] = a0.y; f[r][2] = a1.x; f[r][3] = a1.y;
            }
#pragma unroll
            for (int dy = 0; dy < 3; ++dy)
#pragma unroll
            for (int dx = 0; dx < 3; ++dx) {
                float4 w4 = *(const float4*)&wlds[c][dy * 3 + dx][q * 4];
#pragma unroll
                for (int py = 0; py < 2; ++py)
#pragma unroll
                for (int px = 0; px < 2; ++px) {
                    float fv = f[py + dy][px + dx];
                    acc[py][px][0] += fv * w4.x;
                    acc[py][px][1] += fv * w4.y;
                    acc[py][px][2] += fv * w4.z;
                    acc[py][px][3] += fv * w4.w;
                }
            }
        }
    }

    float* pout = partial + (size_t)kg * (NB * NPOS * OC_TOTAL);
#pragma unroll
    for (int py = 0; py < 2; ++py)
#pragma unroll
    for (int px = 0; px < 2; ++px) {
        int pos = (ty0 + ry0 + py) * FWW + (tx0 + rx0 + px);
        float* op = pout + ((size_t)b * NPOS + pos) * OC_TOTAL + ocbase;
#pragma unroll
        for (int o = 0; o < 4; ++o) {
            int oo = q * 4 + o;
            if (oo < 15) op[oo] = acc[py][px][o];
        }
    }
}

// ---------------- Decode: sum partials + sigmoid + box decode ----------------
__global__ __launch_bounds__(256) void decode_kernel(
    const float* __restrict__ partial,    // [nkg][4,4096,45]
    const float* __restrict__ anchors,    // [36864,4]
    const int* __restrict__ stridep,
    float* __restrict__ boxes,            // [4,36864,4]
    float* __restrict__ scores,           // [4,36864]
    int nkg)
{
    int t = blockIdx.x * 256 + threadIdx.x;   // 4*36864
    int b = t / NANCH;
    int n = t - b * NANCH;
    int pos = n / NA;
    int a = n - pos * NA;
    size_t base = ((size_t)b * NPOS + pos) * OC_TOTAL;
    float cls = 0.f, l0 = 0.f, l1 = 0.f, l2 = 0.f, l3 = 0.f;
    for (int kg = 0; kg < nkg; ++kg) {
        const float* co = partial + (size_t)kg * (NB * NPOS * OC_TOTAL) + base;
        cls += co[a];
        l0 += co[NA + a * 4 + 0];
        l1 += co[NA + a * 4 + 1];
        l2 += co[NA + a * 4 + 2];
        l3 += co[NA + a * 4 + 3];
    }
    float sig = 1.f / (1.f + expf(-cls));
    const float* an = anchors + (size_t)n * 4;
    float ax1 = an[0], ay1 = an[1], ax2 = an[2], ay2 = an[3];
    float aw = ax2 - ax1, ah = ay2 - ay1;
    float acx = ax1 + 0.5f * aw, acy = ay1 + 0.5f * ah;
    float cx = acx + l0 * aw;
    float cy = acy + l1 * ah;
    float w = aw * expf(l2);
    float h = ah * expf(l3);
    float x1 = fminf(fmaxf(cx - 0.5f * w, 0.f), 512.f);
    float y1 = fminf(fmaxf(cy - 0.5f * h, 0.f), 512.f);
    float x2 = fminf(fmaxf(cx + 0.5f * w, 0.f), 512.f);
    float y2 = fminf(fmaxf(cy + 0.5f * h, 0.f), 512.f);
    int stride = stridep[0];
    float msz = 2.f * (float)stride;
    bool valid = (sig > 0.5f) && ((x2 - x1) >= msz) && ((y2 - y1) >= msz);
    ((float4*)boxes)[t] = make_float4(x1, y1, x2, y2);
    scores[t] = valid ? sig : -1.0f;
}

// ---------------- NMS v2: hierarchical chunk-max, dead-chunk skipping ----------------
// grid: 4 blocks (one per batch), 1024 threads (16 waves x 36 chunks each)
__global__ __launch_bounds__(1024) void nms_kernel(
    const float* __restrict__ boxes,   // [4,36864,4]
    const float* __restrict__ scores,  // [4,36864]
    const int* __restrict__ stridep,
    float* __restrict__ d_out,         // eval_boxes at 0, ok at 640
    int* __restrict__ ifb,             // [128][4]
    int* __restrict__ iok)             // [128]
{
    __shared__ float s[NANCH];
    __shared__ float cmax[NCHUNK];
    __shared__ float redv[16];
    __shared__ int   redi[16];
    __shared__ int   bc_sh;
    __shared__ int   fi_sh;
    __shared__ float fs_sh;
    __shared__ float cb[4];
    __shared__ int   picks_sh[MAXROIS];
    __shared__ float pscore_sh[MAXROIS];

    int b = blockIdx.x;
    const float4* Bb4 = (const float4*)(boxes + (size_t)b * NANCH * 4);
    const float* Sb = scores + (size_t)b * NANCH;
    int lane = threadIdx.x & 63;
    int w = threadIdx.x >> 6;

    for (int j = threadIdx.x; j < NANCH; j += 1024) s[j] = Sb[j];
    __syncthreads();

    // init chunk maxes
    for (int k = 0; k < 36; ++k) {
        int ch = w * 36 + k;
        float v = s[ch * 64 + lane];
#pragma unroll
        for (int off = 32; off >= 1; off >>= 1) v = fmaxf(v, __shfl_xor(v, off));
        if (lane == 0) cmax[ch] = v;
    }
    __syncthreads();

    for (int round = 0; round < MAXROIS; ++round) {
        // ---- argmax over chunk maxes (tie -> smallest chunk) ----
        float v = -3.f; int i = 0x7fffffff;
        if (threadIdx.x < NCHUNK) { v = cmax[threadIdx.x]; i = threadIdx.x; }
#pragma unroll
        for (int off = 32; off >= 1; off >>= 1) {
            float ov = __shfl_xor(v, off);
            int   oi = __shfl_xor(i, off);
            if (ov > v || (ov == v && oi < i)) { v = ov; i = oi; }
        }
        if (lane == 0) { redv[w] = v; redi[w] = i; }
        __syncthreads();
        if (threadIdx.x == 0) {
            float bv = redv[0]; int bi = redi[0];
#pragma unroll
            for (int w2 = 1; w2 < 16; ++w2) {
                float ov = redv[w2]; int oi = redi[w2];
                if (ov > bv || (ov == bv && oi < bi)) { bv = ov; bi = oi; }
            }
            bc_sh = bi;
        }
        __syncthreads();
        int bc = bc_sh;
        // ---- argmax within winning chunk (wave 0) ----
        if (w == 0) {
            int j = bc * 64 + lane;
            float vv = s[j]; int ii = j;
#pragma unroll
            for (int off = 32; off >= 1; off >>= 1) {
                float ov = __shfl_xor(vv, off);
                int   oi = __shfl_xor(ii, off);
                if (ov > vv || (ov == vv && oi < ii)) { vv = ov; ii = oi; }
            }
            if (lane == 0) {
                fi_sh = ii; fs_sh = vv;
                picks_sh[round] = ii;
                pscore_sh[round] = vv;
                float4 bb = Bb4[ii];
                cb[0] = bb.x; cb[1] = bb.y; cb[2] = bb.z; cb[3] = bb.w;
            }
        }
        __syncthreads();
        float fs = fs_sh;
        if (fs > 0.f) {
            float px1 = cb[0], py1 = cb[1], px2 = cb[2], py2 = cb[3];
            float parea = (px2 - px1) * (py2 - py1);
            for (int k = 0; k < 36; ++k) {
                int ch = w * 36 + k;
                if (cmax[ch] > 0.f) {
                    int j = ch * 64 + lane;
                    float sv = s[j];
                    float nv = sv;
                    if (sv > 0.f) {
                        float4 bb = Bb4[j];
                        float xx1 = fmaxf(px1, bb.x), yy1 = fmaxf(py1, bb.y);
                        float xx2 = fminf(px2, bb.z), yy2 = fminf(py2, bb.w);
                        float inter = fmaxf(xx2 - xx1, 0.f) * fmaxf(yy2 - yy1, 0.f);
                        float a2 = (bb.z - bb.x) * (bb.w - bb.y);
                        float iou = inter / (parea + a2 - inter + 1e-9f);
                        if (iou > 0.3f) { nv = -1.f; s[j] = -1.f; }
                    }
                    float m = nv;
#pragma unroll
                    for (int off = 32; off >= 1; off >>= 1) m = fmaxf(m, __shfl_xor(m, off));
                    if (lane == 0) cmax[ch] = m;
                }
            }
        }
        __syncthreads();
    }

    // ---- outputs ----
    if (threadIdx.x < MAXROIS) {
        int i = threadIdx.x;
        int idx = picks_sh[i];
        float sc = pscore_sh[i];
        bool okv = sc > 0.f;
        float4 bb = Bb4[idx];
        float x1 = bb.x, y1 = bb.y, x2 = bb.z, y2 = bb.w;
        float* eb = d_out + ((size_t)b * MAXROIS + i) * 5;
        eb[0] = okv ? x1 : 0.f;
        eb[1] = okv ? y1 : 0.f;
        eb[2] = okv ? x2 : 0.f;
        eb[3] = okv ? y2 : 0.f;
        eb[4] = okv ? sc : 0.f;
        d_out[NB * MAXROIS * 5 + b * MAXROIS + i] = okv ? 1.f : 0.f;
        int st = stridep[0];
        int fx1 = min(max(((int)x1) / st, 0), FWW - 1);
        int fy1 = min(max(((int)y1) / st, 0), FHH - 1);
        int fx2 = min(max(((int)x2) / st, fx1 + 1), FWW);
        int fy2 = min(max(((int)y2) / st, fy1 + 1), FHH);
        int r = b * MAXROIS + i;
        ifb[r * 4 + 0] = fx1;
        ifb[r * 4 + 1] = fy1;
        ifb[r * 4 + 2] = fx2;
        ifb[r * 4 + 3] = fy2;
        iok[r] = okv ? 1 : 0;
    }
}

// ---------------- Adaptive max-pool ROI extraction ----------------
__global__ __launch_bounds__(256) void roi_kernel(
    const float* __restrict__ feat,   // [4,256,64,64]
    const int* __restrict__ ifb,      // [128][4]
    const int* __restrict__ iok,      // [128]
    float* __restrict__ out_rois)     // [128,256,7,7]
{
    int r = blockIdx.x;
    int b = r >> 5;
    int c = threadIdx.x;
    float* outp = out_rois + ((size_t)r * CIN + c) * (ROI * ROI);
    if (!iok[r]) {
#pragma unroll
        for (int k = 0; k < ROI * ROI; ++k) outp[k] = 0.f;
        return;
    }
    int x1 = ifb[r * 4 + 0];
    int y1 = ifb[r * 4 + 1];
    int x2 = ifb[r * 4 + 2];
    int y2 = ifb[r * 4 + 3];
    int h = y2 - y1;
    int w = x2 - x1;
    const float* F = feat + (size_t)(b * CIN + c) * NPOS;
#pragma unroll
    for (int i = 0; i < ROI; ++i) {
        int rs = y1 + (i * h) / ROI;
        int re = y1 + ((i + 1) * h + ROI - 1) / ROI;
#pragma unroll
        for (int j = 0; j < ROI; ++j) {
            int csx = x1 + (j * w) / ROI;
            int cex = x1 + ((j + 1) * w + ROI - 1) / ROI;
            float m = NEGV;
            for (int y = rs; y < re; ++y) {
                const float* row = F + y * FWW;
                for (int x = csx; x < cex; ++x) m = fmaxf(m, row[x]);
            }
            outp[i * ROI + j] = m;
        }
    }
}

extern "C" void kernel_launch(void* const* d_in, const int* in_sizes, int n_in,
                              void* d_out, int out_size, void* d_ws, size_t ws_size,
                              hipStream_t stream) {
    const float* feat    = (const float*)d_in[0];
    const float* anchors = (const float*)d_in[1];
    const float* wcls    = (const float*)d_in[2];
    const float* wloc    = (const float*)d_in[3];
    const int*   stridep = (const int*)d_in[4];
    float* out = (float*)d_out;
    float* ws  = (float*)d_ws;

    const size_t P1 = (size_t)NB * NPOS * OC_TOTAL;   // 737280 floats
    int nkg = 4;
    size_t need = (P1 * 4 + 589824 + 147456 + 512 + 128) * 4;
    if (ws_size < need) nkg = 1;

    float* partial = ws;
    float* boxes   = ws + P1 * nkg;
    float* scores  = boxes + (size_t)NB * NANCH * 4;
    int*   ifb     = (int*)(scores + (size_t)NB * NANCH);
    int*   iok     = ifb + 512;

    conv_kernel<<<192 * nkg, 256, 0, stream>>>(feat, wcls, wloc, partial, nkg, CIN / nkg);
    decode_kernel<<<(NB * NANCH) / 256, 256, 0, stream>>>(partial, anchors, stridep, boxes, scores, nkg);
    nms_kernel<<<NB, 1024, 0, stream>>>(boxes, scores, stridep, out, ifb, iok);
    roi_kernel<<<NB * MAXROIS, 256, 0, stream>>>(feat, ifb, iok, out + NB * MAXROIS * 5 + NB * MAXROIS);
}

// Round 3
// 413.761 us; speedup vs baseline: 2.8728x; 2.5155x over previous
//
#include <hip/hip_runtime.h>
#include <hip/hip_bf16.h>

#define FHH 64
#define FWW 64
#define CIN 256
#define NB 4
#define NA 9
#define NANCH 36864
#define NPOS 4096
#define OC_TOTAL 45
#define MAXROIS 32
#define ROI 7
#define NEGV -1e30f
#define CC 32
#define NCHUNK 576   // NANCH / 64

// ---------------- Weight transpose: wT[3][256][9][16] ----------------
__global__ __launch_bounds__(256) void wtrans_kernel(
    const float* __restrict__ wcls,   // [9,256,3,3]
    const float* __restrict__ wloc,   // [36,256,3,3]
    float* __restrict__ wT)           // [3,256,9,16]
{
    int idx = blockIdx.x * 256 + threadIdx.x;   // < 3*256*144 = 110592
    int o = idx & 15;
    int tap = (idx >> 4) % 9;
    int rest = idx / 144;       // g*256 + c
    int c = rest & 255;
    int g = rest >> 8;
    float v = 0.f;
    if (o < 15) {
        int oc = g * 15 + o;
        v = (oc < NA) ? wcls[((size_t)oc * CIN + c) * 9 + tap]
                      : wloc[((size_t)(oc - NA) * CIN + c) * 9 + tap];
    }
    wT[idx] = v;
}

// ---------------- Conv: 16x16 pos tile, 2x2 pos x 4 oc per thread ----------------
// grid: 64 units x (3*nkg) pairs, XCD-swizzled; 256 threads
__global__ __launch_bounds__(256) void conv_kernel(
    const float* __restrict__ feat,    // [4,256,64,64]
    const float* __restrict__ wT,      // [3,256,9,16]
    float* __restrict__ partial,       // [nkg][4,4096,45]
    int nkg, int cpk)
{
    __shared__ float flds[CC][18][18];     // 41472 B
    __shared__ float wlds[CC][9][16];      // 18432 B

    int NP = 3 * nkg;
    int blk = blockIdx.x;
    int low = blk & 7;
    int rest = blk >> 3;
    int pair = rest % NP;
    int uhi = rest / NP;
    int unit = uhi * 8 + low;          // b*16 + tile; same-unit blocks share XCD
    int b = unit >> 4;
    int tile = unit & 15;
    int g = pair / nkg;
    int kg = pair % nkg;

    int ty0 = (tile >> 2) * 16;
    int tx0 = (tile & 3) * 16;

    int pb = threadIdx.x & 63;
    int q  = threadIdx.x >> 6;     // oc quad (wave-uniform)
    int ry0 = (pb >> 3) * 2;
    int rx0 = (pb & 7) * 2;

    int ocbase = g * 15;
    int cbase  = kg * cpk;

    float acc[2][2][4];
#pragma unroll
    for (int py = 0; py < 2; ++py)
#pragma unroll
        for (int px = 0; px < 2; ++px)
#pragma unroll
            for (int o = 0; o < 4; ++o) acc[py][px][o] = 0.f;

    for (int c0 = 0; c0 < cpk; c0 += CC) {
        __syncthreads();
        // stage feature tile 18x18 x CC
        for (int idx = threadIdx.x; idx < CC * 324; idx += 256) {
            int c = idx / 324;
            int r = idx - c * 324;
            int y = r / 18;
            int x = r - y * 18;
            int gy = ty0 + y - 1;
            int gx = tx0 + x - 1;
            float v = 0.f;
            if ((unsigned)gy < FHH && (unsigned)gx < FWW)
                v = feat[((size_t)(b * CIN + cbase + c0 + c) * FHH + gy) * FWW + gx];
            flds[c][y][x] = v;
        }
        // stage weights: contiguous copy from wT[g][cbase+c0 ..][9][16]
        {
            const float4* src = (const float4*)(wT + ((size_t)(g * CIN + cbase + c0)) * 144);
            float4* dst = (float4*)&wlds[0][0][0];
            for (int idx = threadIdx.x; idx < CC * 36; idx += 256)
                dst[idx] = src[idx];
        }
        __syncthreads();

        for (int c = 0; c < CC; ++c) {
            float f[4][4];
#pragma unroll
            for (int r = 0; r < 4; ++r) {
                float2 a0 = *(const float2*)&flds[c][ry0 + r][rx0];
                float2 a1 = *(const float2*)&flds[c][ry0 + r][rx0 + 2];
                f[r][0] = a0.x; f[r][1] = a0.y; f[r][2] = a1.x; f[r][3] = a1.y;
            }
#pragma unroll
            for (int dy = 0; dy < 3; ++dy)
#pragma unroll
            for (int dx = 0; dx < 3; ++dx) {
                float4 w4 = *(const float4*)&wlds[c][dy * 3 + dx][q * 4];
#pragma unroll
                for (int py = 0; py < 2; ++py)
#pragma unroll
                for (int px = 0; px < 2; ++px) {
                    float fv = f[py + dy][px + dx];
                    acc[py][px][0] += fv * w4.x;
                    acc[py][px][1] += fv * w4.y;
                    acc[py][px][2] += fv * w4.z;
                    acc[py][px][3] += fv * w4.w;
                }
            }
        }
    }

    float* pout = partial + (size_t)kg * (NB * NPOS * OC_TOTAL);
#pragma unroll
    for (int py = 0; py < 2; ++py)
#pragma unroll
    for (int px = 0; px < 2; ++px) {
        int pos = (ty0 + ry0 + py) * FWW + (tx0 + rx0 + px);
        float* op = pout + ((size_t)b * NPOS + pos) * OC_TOTAL + ocbase;
#pragma unroll
        for (int o = 0; o < 4; ++o) {
            int oo = q * 4 + o;
            if (oo < 15) op[oo] = acc[py][px][o];
        }
    }
}

// ---------------- Decode ----------------
__global__ __launch_bounds__(256) void decode_kernel(
    const float* __restrict__ partial,
    const float* __restrict__ anchors,
    const int* __restrict__ stridep,
    float* __restrict__ boxes,
    float* __restrict__ scores,
    int nkg)
{
    int t = blockIdx.x * 256 + threadIdx.x;
    int b = t / NANCH;
    int n = t - b * NANCH;
    int pos = n / NA;
    int a = n - pos * NA;
    size_t base = ((size_t)b * NPOS + pos) * OC_TOTAL;
    float cls = 0.f, l0 = 0.f, l1 = 0.f, l2 = 0.f, l3 = 0.f;
    for (int kg = 0; kg < nkg; ++kg) {
        const float* co = partial + (size_t)kg * (NB * NPOS * OC_TOTAL) + base;
        cls += co[a];
        l0 += co[NA + a * 4 + 0];
        l1 += co[NA + a * 4 + 1];
        l2 += co[NA + a * 4 + 2];
        l3 += co[NA + a * 4 + 3];
    }
    float sig = 1.f / (1.f + expf(-cls));
    const float* an = anchors + (size_t)n * 4;
    float ax1 = an[0], ay1 = an[1], ax2 = an[2], ay2 = an[3];
    float aw = ax2 - ax1, ah = ay2 - ay1;
    float acx = ax1 + 0.5f * aw, acy = ay1 + 0.5f * ah;
    float cx = acx + l0 * aw;
    float cy = acy + l1 * ah;
    float w = aw * expf(l2);
    float h = ah * expf(l3);
    float x1 = fminf(fmaxf(cx - 0.5f * w, 0.f), 512.f);
    float y1 = fminf(fmaxf(cy - 0.5f * h, 0.f), 512.f);
    float x2 = fminf(fmaxf(cx + 0.5f * w, 0.f), 512.f);
    float y2 = fminf(fmaxf(cy + 0.5f * h, 0.f), 512.f);
    int stride = stridep[0];
    float msz = 2.f * (float)stride;
    bool valid = (sig > 0.5f) && ((x2 - x1) >= msz) && ((y2 - y1) >= msz);
    ((float4*)boxes)[t] = make_float4(x1, y1, x2, y2);
    scores[t] = valid ? sig : -1.0f;
}

// ---------------- NMS v3: lazy-rejection pop loop, single wave ----------------
// grid: 4 blocks (one per batch), 1024 threads (init), wave 0 pops
__global__ __launch_bounds__(1024) void nms_kernel(
    const float* __restrict__ boxes,
    const float* __restrict__ scores,
    const int* __restrict__ stridep,
    float* __restrict__ d_out,
    int* __restrict__ ifb,
    int* __restrict__ iok)
{
    __shared__ float s[NANCH];             // 144 KB
    __shared__ float2 cmax[NCHUNK];        // (maxval, bitcast argidx)
    __shared__ int   picks_sh[MAXROIS];
    __shared__ float pscore_sh[MAXROIS];

    int b = blockIdx.x;
    const float4* Bb4 = (const float4*)(boxes + (size_t)b * NANCH * 4);
    const float* Sb = scores + (size_t)b * NANCH;
    int lane = threadIdx.x & 63;
    int w = threadIdx.x >> 6;

    // init: load scores to LDS + per-chunk packed argmax
    for (int k = 0; k < 36; ++k) {
        int ch = w * 36 + k;
        int j = ch * 64 + lane;
        float v = Sb[j];
        s[j] = v;
        float bv = v; int bi = j;
#pragma unroll
        for (int off = 32; off >= 1; off >>= 1) {
            float ov = __shfl_xor(bv, off);
            int   oi = __shfl_xor(bi, off);
            if (ov > bv || (ov == bv && oi < bi)) { bv = ov; bi = oi; }
        }
        if (lane == 0) cmax[ch] = make_float2(bv, __int_as_float(bi));
    }
    __syncthreads();
    if (w != 0) return;

    // ---- wave-0 pop loop ----
    float px1 = 0.f, py1 = 0.f, px2 = 0.f, py2 = 0.f, parea = 0.f; // lane's pick
    int np = 0;
    while (np < MAXROIS) {
        // global argmax via packed chunk maxes; lane owns 9 chunks
        float bv = -2.f; int bi = 0x7fffffff;
#pragma unroll
        for (int k = 0; k < 9; ++k) {
            float2 cm = cmax[lane * 9 + k];
            int ci = __float_as_int(cm.y);
            if (cm.x > bv || (cm.x == bv && ci < bi)) { bv = cm.x; bi = ci; }
        }
#pragma unroll
        for (int off = 32; off >= 1; off >>= 1) {
            float ov = __shfl_xor(bv, off);
            int   oi = __shfl_xor(bi, off);
            if (ov > bv || (ov == bv && oi < bi)) { bv = ov; bi = oi; }
        }
        if (bv <= 0.f) break;
        int fi = bi; float fs = bv;

        // candidate box (uniform address -> broadcast load)
        float4 cbb = Bb4[fi];

        // lazy suppression check vs picked boxes (lane i holds pick i)
        bool sup = false;
        if (lane < np) {
            float xx1 = fmaxf(px1, cbb.x), yy1 = fmaxf(py1, cbb.y);
            float xx2 = fminf(px2, cbb.z), yy2 = fminf(py2, cbb.w);
            float inter = fmaxf(xx2 - xx1, 0.f) * fmaxf(yy2 - yy1, 0.f);
            float a2 = (cbb.z - cbb.x) * (cbb.w - cbb.y);
            float iou = inter / (parea + a2 - inter + 1e-9f);
            sup = iou > 0.3f;
        }
        unsigned long long m = __ballot(sup);

        // consume candidate: mark dead, recompute its chunk argmax
        int ch = fi >> 6;
        int j = ch * 64 + lane;
        float sv = (j == fi) ? -1.f : s[j];
        if (j == fi) s[j] = -1.f;
        float nv = sv; int ni = j;
#pragma unroll
        for (int off = 32; off >= 1; off >>= 1) {
            float ov = __shfl_xor(nv, off);
            int   oi = __shfl_xor(ni, off);
            if (ov > nv || (ov == nv && oi < ni)) { nv = ov; ni = oi; }
        }
        if (lane == 0) cmax[ch] = make_float2(nv, __int_as_float(ni));

        if (m == 0ULL) {
            if (lane == np) {
                px1 = cbb.x; py1 = cbb.y; px2 = cbb.z; py2 = cbb.w;
                parea = (px2 - px1) * (py2 - py1);
            }
            picks_sh[np] = fi;
            pscore_sh[np] = fs;
            ++np;
        }
    }

    // ---- outputs (lanes 0..31) ----
    if (lane < MAXROIS) {
        int i = lane;
        bool okv = i < np;
        int idx = okv ? picks_sh[i] : 0;
        float sc = okv ? pscore_sh[i] : -1.f;
        float4 bb = Bb4[idx];
        float* eb = d_out + ((size_t)b * MAXROIS + i) * 5;
        eb[0] = okv ? bb.x : 0.f;
        eb[1] = okv ? bb.y : 0.f;
        eb[2] = okv ? bb.z : 0.f;
        eb[3] = okv ? bb.w : 0.f;
        eb[4] = okv ? sc : 0.f;
        d_out[NB * MAXROIS * 5 + b * MAXROIS + i] = okv ? 1.f : 0.f;
        int st = stridep[0];
        int fx1 = min(max(((int)bb.x) / st, 0), FWW - 1);
        int fy1 = min(max(((int)bb.y) / st, 0), FHH - 1);
        int fx2 = min(max(((int)bb.z) / st, fx1 + 1), FWW);
        int fy2 = min(max(((int)bb.w) / st, fy1 + 1), FHH);
        int r = b * MAXROIS + i;
        ifb[r * 4 + 0] = fx1;
        ifb[r * 4 + 1] = fy1;
        ifb[r * 4 + 2] = fx2;
        ifb[r * 4 + 3] = fy2;
        iok[r] = okv ? 1 : 0;
    }
}

// ---------------- Adaptive max-pool ROI extraction ----------------
__global__ __launch_bounds__(256) void roi_kernel(
    const float* __restrict__ feat,
    const int* __restrict__ ifb,
    const int* __restrict__ iok,
    float* __restrict__ out_rois)
{
    int r = blockIdx.x;
    int b = r >> 5;
    int c = threadIdx.x;
    float* outp = out_rois + ((size_t)r * CIN + c) * (ROI * ROI);
    if (!iok[r]) {
#pragma unroll
        for (int k = 0; k < ROI * ROI; ++k) outp[k] = 0.f;
        return;
    }
    int x1 = ifb[r * 4 + 0];
    int y1 = ifb[r * 4 + 1];
    int x2 = ifb[r * 4 + 2];
    int y2 = ifb[r * 4 + 3];
    int h = y2 - y1;
    int w = x2 - x1;
    const float* F = feat + (size_t)(b * CIN + c) * NPOS;
#pragma unroll
    for (int i = 0; i < ROI; ++i) {
        int rs = y1 + (i * h) / ROI;
        int re = y1 + ((i + 1) * h + ROI - 1) / ROI;
#pragma unroll
        for (int j = 0; j < ROI; ++j) {
            int csx = x1 + (j * w) / ROI;
            int cex = x1 + ((j + 1) * w + ROI - 1) / ROI;
            float m = NEGV;
            for (int y = rs; y < re; ++y) {
                const float* row = F + y * FWW;
                for (int x = csx; x < cex; ++x) m = fmaxf(m, row[x]);
            }
            outp[i * ROI + j] = m;
        }
    }
}

extern "C" void kernel_launch(void* const* d_in, const int* in_sizes, int n_in,
                              void* d_out, int out_size, void* d_ws, size_t ws_size,
                              hipStream_t stream) {
    const float* feat    = (const float*)d_in[0];
    const float* anchors = (const float*)d_in[1];
    const float* wcls    = (const float*)d_in[2];
    const float* wloc    = (const float*)d_in[3];
    const int*   stridep = (const int*)d_in[4];
    float* out = (float*)d_out;
    float* ws  = (float*)d_ws;

    const size_t P1 = (size_t)NB * NPOS * OC_TOTAL;   // 737280 floats
    const size_t WTN = 3 * 256 * 144;                 // 110592 floats
    int nkg = 4;
    size_t need = (P1 * 4 + (size_t)NB * NANCH * 5 + WTN + 1024) * 4;
    if (ws_size < need) nkg = 1;

    float* partial = ws;
    float* boxes   = partial + P1 * nkg;
    float* scores  = boxes + (size_t)NB * NANCH * 4;
    float* wT      = scores + (size_t)NB * NANCH;
    int*   ifb     = (int*)(wT + WTN);
    int*   iok     = ifb + 512;

    wtrans_kernel<<<432, 256, 0, stream>>>(wcls, wloc, wT);
    conv_kernel<<<64 * 3 * nkg, 256, 0, stream>>>(feat, wT, partial, nkg, CIN / nkg);
    decode_kernel<<<(NB * NANCH) / 256, 256, 0, stream>>>(partial, anchors, stridep, boxes, scores, nkg);
    nms_kernel<<<NB, 1024, 0, stream>>>(boxes, scores, stridep, out, ifb, iok);
    roi_kernel<<<NB * MAXROIS, 256, 0, stream>>>(feat, ifb, iok, out + NB * MAXROIS * 5 + NB * MAXROIS);
}

// Round 4
// 242.400 us; speedup vs baseline: 4.9037x; 1.7069x over previous
//
#include <hip/hip_runtime.h>
#include <hip/hip_bf16.h>

#define FHH 64
#define FWW 64
#define CIN 256
#define NB 4
#define NA 9
#define NANCH 36864
#define NPOS 4096
#define OC_TOTAL 45
#define MAXROIS 32
#define ROI 7
#define NEGV -1e30f
#define CC 32
#define NCHUNK 576   // NANCH / 64

// ---------------- Weight transpose: wT[3][256][9][16] ----------------
__global__ __launch_bounds__(256) void wtrans_kernel(
    const float* __restrict__ wcls,   // [9,256,3,3]
    const float* __restrict__ wloc,   // [36,256,3,3]
    float* __restrict__ wT)           // [3,256,9,16]
{
    int idx = blockIdx.x * 256 + threadIdx.x;   // < 3*256*144 = 110592
    int o = idx & 15;
    int tap = (idx >> 4) % 9;
    int rest = idx / 144;       // g*256 + c
    int c = rest & 255;
    int g = rest >> 8;
    float v = 0.f;
    if (o < 15) {
        int oc = g * 15 + o;
        v = (oc < NA) ? wcls[((size_t)oc * CIN + c) * 9 + tap]
                      : wloc[((size_t)(oc - NA) * CIN + c) * 9 + tap];
    }
    wT[idx] = v;
}

// ---------------- Conv: 16x16 pos tile, 2x2 pos x 4 oc per thread ----------------
__global__ __launch_bounds__(256) void conv_kernel(
    const float* __restrict__ feat,    // [4,256,64,64]
    const float* __restrict__ wT,      // [3,256,9,16]
    float* __restrict__ partial,       // [nkg][4,4096,45]
    int nkg, int cpk)
{
    __shared__ float flds[CC][18][18];     // 41472 B
    __shared__ float wlds[CC][9][16];      // 18432 B

    int NP = 3 * nkg;
    int blk = blockIdx.x;
    int low = blk & 7;
    int rest = blk >> 3;
    int pair = rest % NP;
    int uhi = rest / NP;
    int unit = uhi * 8 + low;          // b*16 + tile; same-unit blocks share XCD
    int b = unit >> 4;
    int tile = unit & 15;
    int g = pair / nkg;
    int kg = pair % nkg;

    int ty0 = (tile >> 2) * 16;
    int tx0 = (tile & 3) * 16;

    int pb = threadIdx.x & 63;
    int q  = threadIdx.x >> 6;     // oc quad (wave-uniform)
    int ry0 = (pb >> 3) * 2;
    int rx0 = (pb & 7) * 2;

    int ocbase = g * 15;
    int cbase  = kg * cpk;

    float acc[2][2][4];
#pragma unroll
    for (int py = 0; py < 2; ++py)
#pragma unroll
        for (int px = 0; px < 2; ++px)
#pragma unroll
            for (int o = 0; o < 4; ++o) acc[py][px][o] = 0.f;

    for (int c0 = 0; c0 < cpk; c0 += CC) {
        __syncthreads();
        for (int idx = threadIdx.x; idx < CC * 324; idx += 256) {
            int c = idx / 324;
            int r = idx - c * 324;
            int y = r / 18;
            int x = r - y * 18;
            int gy = ty0 + y - 1;
            int gx = tx0 + x - 1;
            float v = 0.f;
            if ((unsigned)gy < FHH && (unsigned)gx < FWW)
                v = feat[((size_t)(b * CIN + cbase + c0 + c) * FHH + gy) * FWW + gx];
            flds[c][y][x] = v;
        }
        {
            const float4* src = (const float4*)(wT + ((size_t)(g * CIN + cbase + c0)) * 144);
            float4* dst = (float4*)&wlds[0][0][0];
            for (int idx = threadIdx.x; idx < CC * 36; idx += 256)
                dst[idx] = src[idx];
        }
        __syncthreads();

        for (int c = 0; c < CC; ++c) {
            float f[4][4];
#pragma unroll
            for (int r = 0; r < 4; ++r) {
                float2 a0 = *(const float2*)&flds[c][ry0 + r][rx0];
                float2 a1 = *(const float2*)&flds[c][ry0 + r][rx0 + 2];
                f[r][0] = a0.x; f[r][1] = a0.y; f[r][2] = a1.x; f[r][3] = a1.y;
            }
#pragma unroll
            for (int dy = 0; dy < 3; ++dy)
#pragma unroll
            for (int dx = 0; dx < 3; ++dx) {
                float4 w4 = *(const float4*)&wlds[c][dy * 3 + dx][q * 4];
#pragma unroll
                for (int py = 0; py < 2; ++py)
#pragma unroll
                for (int px = 0; px < 2; ++px) {
                    float fv = f[py + dy][px + dx];
                    acc[py][px][0] += fv * w4.x;
                    acc[py][px][1] += fv * w4.y;
                    acc[py][px][2] += fv * w4.z;
                    acc[py][px][3] += fv * w4.w;
                }
            }
        }
    }

    float* pout = partial + (size_t)kg * (NB * NPOS * OC_TOTAL);
#pragma unroll
    for (int py = 0; py < 2; ++py)
#pragma unroll
    for (int px = 0; px < 2; ++px) {
        int pos = (ty0 + ry0 + py) * FWW + (tx0 + rx0 + px);
        float* op = pout + ((size_t)b * NPOS + pos) * OC_TOTAL + ocbase;
#pragma unroll
        for (int o = 0; o < 4; ++o) {
            int oo = q * 4 + o;
            if (oo < 15) op[oo] = acc[py][px][o];
        }
    }
}

// ---------------- Decode ----------------
__global__ __launch_bounds__(256) void decode_kernel(
    const float* __restrict__ partial,
    const float* __restrict__ anchors,
    const int* __restrict__ stridep,
    float* __restrict__ boxes,
    float* __restrict__ scores,
    int nkg)
{
    int t = blockIdx.x * 256 + threadIdx.x;
    int b = t / NANCH;
    int n = t - b * NANCH;
    int pos = n / NA;
    int a = n - pos * NA;
    size_t base = ((size_t)b * NPOS + pos) * OC_TOTAL;
    float cls = 0.f, l0 = 0.f, l1 = 0.f, l2 = 0.f, l3 = 0.f;
    for (int kg = 0; kg < nkg; ++kg) {
        const float* co = partial + (size_t)kg * (NB * NPOS * OC_TOTAL) + base;
        cls += co[a];
        l0 += co[NA + a * 4 + 0];
        l1 += co[NA + a * 4 + 1];
        l2 += co[NA + a * 4 + 2];
        l3 += co[NA + a * 4 + 3];
    }
    float sig = 1.f / (1.f + expf(-cls));
    const float* an = anchors + (size_t)n * 4;
    float ax1 = an[0], ay1 = an[1], ax2 = an[2], ay2 = an[3];
    float aw = ax2 - ax1, ah = ay2 - ay1;
    float acx = ax1 + 0.5f * aw, acy = ay1 + 0.5f * ah;
    float cx = acx + l0 * aw;
    float cy = acy + l1 * ah;
    float w = aw * expf(l2);
    float h = ah * expf(l3);
    float x1 = fminf(fmaxf(cx - 0.5f * w, 0.f), 512.f);
    float y1 = fminf(fmaxf(cy - 0.5f * h, 0.f), 512.f);
    float x2 = fminf(fmaxf(cx + 0.5f * w, 0.f), 512.f);
    float y2 = fminf(fmaxf(cy + 0.5f * h, 0.f), 512.f);
    int stride = stridep[0];
    float msz = 2.f * (float)stride;
    bool valid = (sig > 0.5f) && ((x2 - x1) >= msz) && ((y2 - y1) >= msz);
    ((float4*)boxes)[t] = make_float4(x1, y1, x2, y2);
    scores[t] = valid ? sig : -1.0f;
}

// ---------------- NMS v3: lazy-rejection pop loop, single wave ----------------
__global__ __launch_bounds__(1024) void nms_kernel(
    const float* __restrict__ boxes,
    const float* __restrict__ scores,
    const int* __restrict__ stridep,
    float* __restrict__ d_out,
    int* __restrict__ ifb,
    int* __restrict__ iok)
{
    __shared__ float s[NANCH];             // 144 KB
    __shared__ float2 cmax[NCHUNK];
    __shared__ int   picks_sh[MAXROIS];
    __shared__ float pscore_sh[MAXROIS];

    int b = blockIdx.x;
    const float4* Bb4 = (const float4*)(boxes + (size_t)b * NANCH * 4);
    const float* Sb = scores + (size_t)b * NANCH;
    int lane = threadIdx.x & 63;
    int w = threadIdx.x >> 6;

    for (int k = 0; k < 36; ++k) {
        int ch = w * 36 + k;
        int j = ch * 64 + lane;
        float v = Sb[j];
        s[j] = v;
        float bv = v; int bi = j;
#pragma unroll
        for (int off = 32; off >= 1; off >>= 1) {
            float ov = __shfl_xor(bv, off);
            int   oi = __shfl_xor(bi, off);
            if (ov > bv || (ov == bv && oi < bi)) { bv = ov; bi = oi; }
        }
        if (lane == 0) cmax[ch] = make_float2(bv, __int_as_float(bi));
    }
    __syncthreads();
    if (w != 0) return;

    float px1 = 0.f, py1 = 0.f, px2 = 0.f, py2 = 0.f, parea = 0.f;
    int np = 0;
    while (np < MAXROIS) {
        float bv = -2.f; int bi = 0x7fffffff;
#pragma unroll
        for (int k = 0; k < 9; ++k) {
            float2 cm = cmax[lane * 9 + k];
            int ci = __float_as_int(cm.y);
            if (cm.x > bv || (cm.x == bv && ci < bi)) { bv = cm.x; bi = ci; }
        }
#pragma unroll
        for (int off = 32; off >= 1; off >>= 1) {
            float ov = __shfl_xor(bv, off);
            int   oi = __shfl_xor(bi, off);
            if (ov > bv || (ov == bv && oi < bi)) { bv = ov; bi = oi; }
        }
        if (bv <= 0.f) break;
        int fi = bi; float fs = bv;

        float4 cbb = Bb4[fi];

        bool sup = false;
        if (lane < np) {
            float xx1 = fmaxf(px1, cbb.x), yy1 = fmaxf(py1, cbb.y);
            float xx2 = fminf(px2, cbb.z), yy2 = fminf(py2, cbb.w);
            float inter = fmaxf(xx2 - xx1, 0.f) * fmaxf(yy2 - yy1, 0.f);
            float a2 = (cbb.z - cbb.x) * (cbb.w - cbb.y);
            float iou = inter / (parea + a2 - inter + 1e-9f);
            sup = iou > 0.3f;
        }
        unsigned long long m = __ballot(sup);

        int ch = fi >> 6;
        int j = ch * 64 + lane;
        float sv = (j == fi) ? -1.f : s[j];
        if (j == fi) s[j] = -1.f;
        float nv = sv; int ni = j;
#pragma unroll
        for (int off = 32; off >= 1; off >>= 1) {
            float ov = __shfl_xor(nv, off);
            int   oi = __shfl_xor(ni, off);
            if (ov > nv || (ov == nv && oi < ni)) { nv = ov; ni = oi; }
        }
        if (lane == 0) cmax[ch] = make_float2(nv, __int_as_float(ni));

        if (m == 0ULL) {
            if (lane == np) {
                px1 = cbb.x; py1 = cbb.y; px2 = cbb.z; py2 = cbb.w;
                parea = (px2 - px1) * (py2 - py1);
            }
            picks_sh[np] = fi;
            pscore_sh[np] = fs;
            ++np;
        }
    }

    if (lane < MAXROIS) {
        int i = lane;
        bool okv = i < np;
        int idx = okv ? picks_sh[i] : 0;
        float sc = okv ? pscore_sh[i] : -1.f;
        float4 bb = Bb4[idx];
        float* eb = d_out + ((size_t)b * MAXROIS + i) * 5;
        eb[0] = okv ? bb.x : 0.f;
        eb[1] = okv ? bb.y : 0.f;
        eb[2] = okv ? bb.z : 0.f;
        eb[3] = okv ? bb.w : 0.f;
        eb[4] = okv ? sc : 0.f;
        d_out[NB * MAXROIS * 5 + b * MAXROIS + i] = okv ? 1.f : 0.f;
        int st = stridep[0];
        int fx1 = min(max(((int)bb.x) / st, 0), FWW - 1);
        int fy1 = min(max(((int)bb.y) / st, 0), FHH - 1);
        int fx2 = min(max(((int)bb.z) / st, fx1 + 1), FWW);
        int fy2 = min(max(((int)bb.w) / st, fy1 + 1), FHH);
        int r = b * MAXROIS + i;
        ifb[r * 4 + 0] = fx1;
        ifb[r * 4 + 1] = fy1;
        ifb[r * 4 + 2] = fx2;
        ifb[r * 4 + 3] = fy2;
        iok[r] = okv ? 1 : 0;
    }
}

// ---------------- ROI v2: one thread per (roi, channel, bin) ----------------
// grid: 128*256*49/256 = 6272 blocks, 256 threads
__global__ __launch_bounds__(256) void roi_kernel(
    const float* __restrict__ feat,   // [4,256,64,64]
    const int* __restrict__ ifb,      // [128][4]
    const int* __restrict__ iok,      // [128]
    float* __restrict__ out_rois)     // [128,256,7,7]
{
    int t = blockIdx.x * 256 + threadIdx.x;   // == output flat index
    int bin = t % 49;
    int rc = t / 49;
    int c = rc & 255;
    int r = rc >> 8;
    int i = bin / 7;
    int j = bin - i * 7;

    if (!iok[r]) { out_rois[t] = 0.f; return; }

    int x1 = ifb[r * 4 + 0];
    int y1 = ifb[r * 4 + 1];
    int x2 = ifb[r * 4 + 2];
    int y2 = ifb[r * 4 + 3];
    int h = y2 - y1;
    int w = x2 - x1;
    int b = r >> 5;

    int rs = y1 + (i * h) / ROI;
    int re = y1 + ((i + 1) * h + ROI - 1) / ROI;
    int cs = x1 + (j * w) / ROI;
    int ce = x1 + ((j + 1) * w + ROI - 1) / ROI;

    const float* F = feat + (size_t)(b * CIN + c) * NPOS;
    float m = NEGV;
    for (int y = rs; y < re; ++y) {
        const float* row = F + y * FWW;
        for (int x = cs; x < ce; ++x) m = fmaxf(m, row[x]);
    }
    out_rois[t] = m;
}

extern "C" void kernel_launch(void* const* d_in, const int* in_sizes, int n_in,
                              void* d_out, int out_size, void* d_ws, size_t ws_size,
                              hipStream_t stream) {
    const float* feat    = (const float*)d_in[0];
    const float* anchors = (const float*)d_in[1];
    const float* wcls    = (const float*)d_in[2];
    const float* wloc    = (const float*)d_in[3];
    const int*   stridep = (const int*)d_in[4];
    float* out = (float*)d_out;
    float* ws  = (float*)d_ws;

    const size_t P1 = (size_t)NB * NPOS * OC_TOTAL;   // 737280 floats
    const size_t WTN = 3 * 256 * 144;                 // 110592 floats
    int nkg = 4;
    size_t need = (P1 * 4 + (size_t)NB * NANCH * 5 + WTN + 1024) * 4;
    if (ws_size < need) nkg = 1;

    float* partial = ws;
    float* boxes   = partial + P1 * nkg;
    float* scores  = boxes + (size_t)NB * NANCH * 4;
    float* wT      = scores + (size_t)NB * NANCH;
    int*   ifb     = (int*)(wT + WTN);
    int*   iok     = ifb + 512;

    wtrans_kernel<<<432, 256, 0, stream>>>(wcls, wloc, wT);
    conv_kernel<<<64 * 3 * nkg, 256, 0, stream>>>(feat, wT, partial, nkg, CIN / nkg);
    decode_kernel<<<(NB * NANCH) / 256, 256, 0, stream>>>(partial, anchors, stridep, boxes, scores, nkg);
    nms_kernel<<<NB, 1024, 0, stream>>>(boxes, scores, stridep, out, ifb, iok);
    roi_kernel<<<(NB * MAXROIS * CIN * 49) / 256, 256, 0, stream>>>(feat, ifb, iok, out + NB * MAXROIS * 5 + NB * MAXROIS);
}

// Round 5
// 205.296 us; speedup vs baseline: 5.7899x; 1.1807x over previous
//
#include <hip/hip_runtime.h>
#include <hip/hip_bf16.h>

#define FHH 64
#define FWW 64
#define CIN 256
#define NB 4
#define NA 9
#define NANCH 36864
#define NPOS 4096
#define OC_TOTAL 45
#define MAXROIS 32
#define ROI 7
#define NEGV -1e30f
#define CC 16
#define NCHUNK 576   // NANCH / 64

// ---------------- Weight transpose: wT[3][256][9][16] ----------------
__global__ __launch_bounds__(256) void wtrans_kernel(
    const float* __restrict__ wcls,   // [9,256,3,3]
    const float* __restrict__ wloc,   // [36,256,3,3]
    float* __restrict__ wT)           // [3,256,9,16]
{
    int idx = blockIdx.x * 256 + threadIdx.x;   // < 3*256*144 = 110592
    int o = idx & 15;
    int tap = (idx >> 4) % 9;
    int rest = idx / 144;       // g*256 + c
    int c = rest & 255;
    int g = rest >> 8;
    float v = 0.f;
    if (o < 15) {
        int oc = g * 15 + o;
        v = (oc < NA) ? wcls[((size_t)oc * CIN + c) * 9 + tap]
                      : wloc[((size_t)(oc - NA) * CIN + c) * 9 + tap];
    }
    wT[idx] = v;
}

// ---------------- Conv: 16x16 pos tile, 2x2 pos x 4 oc per thread ----------------
// CC=16: LDS 32.3 KB -> 4 blocks/CU capacity; 768 blocks all resident (12 waves/CU)
__global__ __launch_bounds__(256) void conv_kernel(
    const float* __restrict__ feat,    // [4,256,64,64]
    const float* __restrict__ wT,      // [3,256,9,16]
    float* __restrict__ partial,       // [nkg][4,4096,45]
    int nkg, int cpk)
{
    __shared__ float flds[CC][18][20];     // padded row: 2-way (free) bank map
    __shared__ float wlds[CC][9][16];      // 9216 B

    int NP = 3 * nkg;
    int blk = blockIdx.x;
    int low = blk & 7;
    int rest = blk >> 3;
    int pair = rest % NP;
    int uhi = rest / NP;
    int unit = uhi * 8 + low;          // b*16 + tile; same-unit blocks share XCD
    int b = unit >> 4;
    int tile = unit & 15;
    int g = pair / nkg;
    int kg = pair % nkg;

    int ty0 = (tile >> 2) * 16;
    int tx0 = (tile & 3) * 16;

    int pb = threadIdx.x & 63;
    int q  = threadIdx.x >> 6;     // oc quad (wave-uniform)
    int ry0 = (pb >> 3) * 2;
    int rx0 = (pb & 7) * 2;

    int ocbase = g * 15;
    int cbase  = kg * cpk;

    float acc[2][2][4];
#pragma unroll
    for (int py = 0; py < 2; ++py)
#pragma unroll
        for (int px = 0; px < 2; ++px)
#pragma unroll
            for (int o = 0; o < 4; ++o) acc[py][px][o] = 0.f;

    for (int c0 = 0; c0 < cpk; c0 += CC) {
        __syncthreads();
        for (int idx = threadIdx.x; idx < CC * 324; idx += 256) {
            int c = idx / 324;
            int r = idx - c * 324;
            int y = r / 18;
            int x = r - y * 18;
            int gy = ty0 + y - 1;
            int gx = tx0 + x - 1;
            float v = 0.f;
            if ((unsigned)gy < FHH && (unsigned)gx < FWW)
                v = feat[((size_t)(b * CIN + cbase + c0 + c) * FHH + gy) * FWW + gx];
            flds[c][y][x] = v;
        }
        {
            const float4* src = (const float4*)(wT + ((size_t)(g * CIN + cbase + c0)) * 144);
            float4* dst = (float4*)&wlds[0][0][0];
            for (int idx = threadIdx.x; idx < CC * 36; idx += 256)
                dst[idx] = src[idx];
        }
        __syncthreads();

        for (int c = 0; c < CC; ++c) {
            float f[4][4];
#pragma unroll
            for (int r = 0; r < 4; ++r) {
                float2 a0 = *(const float2*)&flds[c][ry0 + r][rx0];
                float2 a1 = *(const float2*)&flds[c][ry0 + r][rx0 + 2];
                f[r][0] = a0.x; f[r][1] = a0.y; f[r][2] = a1.x; f[r][3] = a1.y;
            }
#pragma unroll
            for (int dy = 0; dy < 3; ++dy)
#pragma unroll
            for (int dx = 0; dx < 3; ++dx) {
                float4 w4 = *(const float4*)&wlds[c][dy * 3 + dx][q * 4];
#pragma unroll
                for (int py = 0; py < 2; ++py)
#pragma unroll
                for (int px = 0; px < 2; ++px) {
                    float fv = f[py + dy][px + dx];
                    acc[py][px][0] += fv * w4.x;
                    acc[py][px][1] += fv * w4.y;
                    acc[py][px][2] += fv * w4.z;
                    acc[py][px][3] += fv * w4.w;
                }
            }
        }
    }

    float* pout = partial + (size_t)kg * (NB * NPOS * OC_TOTAL);
#pragma unroll
    for (int py = 0; py < 2; ++py)
#pragma unroll
    for (int px = 0; px < 2; ++px) {
        int pos = (ty0 + ry0 + py) * FWW + (tx0 + rx0 + px);
        float* op = pout + ((size_t)b * NPOS + pos) * OC_TOTAL + ocbase;
#pragma unroll
        for (int o = 0; o < 4; ++o) {
            int oo = q * 4 + o;
            if (oo < 15) op[oo] = acc[py][px][o];
        }
    }
}

// ---------------- Decode ----------------
__global__ __launch_bounds__(256) void decode_kernel(
    const float* __restrict__ partial,
    const float* __restrict__ anchors,
    const int* __restrict__ stridep,
    float* __restrict__ boxes,
    float* __restrict__ scores,
    int nkg)
{
    int t = blockIdx.x * 256 + threadIdx.x;
    int b = t / NANCH;
    int n = t - b * NANCH;
    int pos = n / NA;
    int a = n - pos * NA;
    size_t base = ((size_t)b * NPOS + pos) * OC_TOTAL;
    float cls = 0.f, l0 = 0.f, l1 = 0.f, l2 = 0.f, l3 = 0.f;
    for (int kg = 0; kg < nkg; ++kg) {
        const float* co = partial + (size_t)kg * (NB * NPOS * OC_TOTAL) + base;
        cls += co[a];
        l0 += co[NA + a * 4 + 0];
        l1 += co[NA + a * 4 + 1];
        l2 += co[NA + a * 4 + 2];
        l3 += co[NA + a * 4 + 3];
    }
    float sig = 1.f / (1.f + expf(-cls));
    const float* an = anchors + (size_t)n * 4;
    float ax1 = an[0], ay1 = an[1], ax2 = an[2], ay2 = an[3];
    float aw = ax2 - ax1, ah = ay2 - ay1;
    float acx = ax1 + 0.5f * aw, acy = ay1 + 0.5f * ah;
    float cx = acx + l0 * aw;
    float cy = acy + l1 * ah;
    float w = aw * expf(l2);
    float h = ah * expf(l3);
    float x1 = fminf(fmaxf(cx - 0.5f * w, 0.f), 512.f);
    float y1 = fminf(fmaxf(cy - 0.5f * h, 0.f), 512.f);
    float x2 = fminf(fmaxf(cx + 0.5f * w, 0.f), 512.f);
    float y2 = fminf(fmaxf(cy + 0.5f * h, 0.f), 512.f);
    int stride = stridep[0];
    float msz = 2.f * (float)stride;
    bool valid = (sig > 0.5f) && ((x2 - x1) >= msz) && ((y2 - y1) >= msz);
    ((float4*)boxes)[t] = make_float4(x1, y1, x2, y2);
    scores[t] = valid ? sig : -1.0f;
}

// ---------------- NMS v3: lazy-rejection pop loop, single wave ----------------
__global__ __launch_bounds__(1024) void nms_kernel(
    const float* __restrict__ boxes,
    const float* __restrict__ scores,
    const int* __restrict__ stridep,
    float* __restrict__ d_out,
    int* __restrict__ ifb,
    int* __restrict__ iok)
{
    __shared__ float s[NANCH];             // 144 KB
    __shared__ float2 cmax[NCHUNK];
    __shared__ int   picks_sh[MAXROIS];
    __shared__ float pscore_sh[MAXROIS];

    int b = blockIdx.x;
    const float4* Bb4 = (const float4*)(boxes + (size_t)b * NANCH * 4);
    const float* Sb = scores + (size_t)b * NANCH;
    int lane = threadIdx.x & 63;
    int w = threadIdx.x >> 6;

    for (int k = 0; k < 36; ++k) {
        int ch = w * 36 + k;
        int j = ch * 64 + lane;
        float v = Sb[j];
        s[j] = v;
        float bv = v; int bi = j;
#pragma unroll
        for (int off = 32; off >= 1; off >>= 1) {
            float ov = __shfl_xor(bv, off);
            int   oi = __shfl_xor(bi, off);
            if (ov > bv || (ov == bv && oi < bi)) { bv = ov; bi = oi; }
        }
        if (lane == 0) cmax[ch] = make_float2(bv, __int_as_float(bi));
    }
    __syncthreads();
    if (w != 0) return;

    float px1 = 0.f, py1 = 0.f, px2 = 0.f, py2 = 0.f, parea = 0.f;
    int np = 0;
    while (np < MAXROIS) {
        float bv = -2.f; int bi = 0x7fffffff;
#pragma unroll
        for (int k = 0; k < 9; ++k) {
            float2 cm = cmax[lane * 9 + k];
            int ci = __float_as_int(cm.y);
            if (cm.x > bv || (cm.x == bv && ci < bi)) { bv = cm.x; bi = ci; }
        }
#pragma unroll
        for (int off = 32; off >= 1; off >>= 1) {
            float ov = __shfl_xor(bv, off);
            int   oi = __shfl_xor(bi, off);
            if (ov > bv || (ov == bv && oi < bi)) { bv = ov; bi = oi; }
        }
        if (bv <= 0.f) break;
        int fi = bi; float fs = bv;

        float4 cbb = Bb4[fi];

        bool sup = false;
        if (lane < np) {
            float xx1 = fmaxf(px1, cbb.x), yy1 = fmaxf(py1, cbb.y);
            float xx2 = fminf(px2, cbb.z), yy2 = fminf(py2, cbb.w);
            float inter = fmaxf(xx2 - xx1, 0.f) * fmaxf(yy2 - yy1, 0.f);
            float a2 = (cbb.z - cbb.x) * (cbb.w - cbb.y);
            float iou = inter / (parea + a2 - inter + 1e-9f);
            sup = iou > 0.3f;
        }
        unsigned long long m = __ballot(sup);

        int ch = fi >> 6;
        int j = ch * 64 + lane;
        float sv = (j == fi) ? -1.f : s[j];
        if (j == fi) s[j] = -1.f;
        float nv = sv; int ni = j;
#pragma unroll
        for (int off = 32; off >= 1; off >>= 1) {
            float ov = __shfl_xor(nv, off);
            int   oi = __shfl_xor(ni, off);
            if (ov > nv || (ov == nv && oi < ni)) { nv = ov; ni = oi; }
        }
        if (lane == 0) cmax[ch] = make_float2(nv, __int_as_float(ni));

        if (m == 0ULL) {
            if (lane == np) {
                px1 = cbb.x; py1 = cbb.y; px2 = cbb.z; py2 = cbb.w;
                parea = (px2 - px1) * (py2 - py1);
            }
            picks_sh[np] = fi;
            pscore_sh[np] = fs;
            ++np;
        }
    }

    if (lane < MAXROIS) {
        int i = lane;
        bool okv = i < np;
        int idx = okv ? picks_sh[i] : 0;
        float sc = okv ? pscore_sh[i] : -1.f;
        float4 bb = Bb4[idx];
        float* eb = d_out + ((size_t)b * MAXROIS + i) * 5;
        eb[0] = okv ? bb.x : 0.f;
        eb[1] = okv ? bb.y : 0.f;
        eb[2] = okv ? bb.z : 0.f;
        eb[3] = okv ? bb.w : 0.f;
        eb[4] = okv ? sc : 0.f;
        d_out[NB * MAXROIS * 5 + b * MAXROIS + i] = okv ? 1.f : 0.f;
        int st = stridep[0];
        int fx1 = min(max(((int)bb.x) / st, 0), FWW - 1);
        int fy1 = min(max(((int)bb.y) / st, 0), FHH - 1);
        int fx2 = min(max(((int)bb.z) / st, fx1 + 1), FWW);
        int fy2 = min(max(((int)bb.w) / st, fy1 + 1), FHH);
        int r = b * MAXROIS + i;
        ifb[r * 4 + 0] = fx1;
        ifb[r * 4 + 1] = fy1;
        ifb[r * 4 + 2] = fx2;
        ifb[r * 4 + 3] = fy2;
        iok[r] = okv ? 1 : 0;
    }
}

// ---------------- ROI v2: one thread per (roi, channel, bin) ----------------
__global__ __launch_bounds__(256) void roi_kernel(
    const float* __restrict__ feat,   // [4,256,64,64]
    const int* __restrict__ ifb,      // [128][4]
    const int* __restrict__ iok,      // [128]
    float* __restrict__ out_rois)     // [128,256,7,7]
{
    int t = blockIdx.x * 256 + threadIdx.x;   // == output flat index
    int bin = t % 49;
    int rc = t / 49;
    int c = rc & 255;
    int r = rc >> 8;
    int i = bin / 7;
    int j = bin - i * 7;

    if (!iok[r]) { out_rois[t] = 0.f; return; }

    int x1 = ifb[r * 4 + 0];
    int y1 = ifb[r * 4 + 1];
    int x2 = ifb[r * 4 + 2];
    int y2 = ifb[r * 4 + 3];
    int h = y2 - y1;
    int w = x2 - x1;
    int b = r >> 5;

    int rs = y1 + (i * h) / ROI;
    int re = y1 + ((i + 1) * h + ROI - 1) / ROI;
    int cs = x1 + (j * w) / ROI;
    int ce = x1 + ((j + 1) * w + ROI - 1) / ROI;

    const float* F = feat + (size_t)(b * CIN + c) * NPOS;
    float m = NEGV;
    for (int y = rs; y < re; ++y) {
        const float* row = F + y * FWW;
        for (int x = cs; x < ce; ++x) m = fmaxf(m, row[x]);
    }
    out_rois[t] = m;
}

extern "C" void kernel_launch(void* const* d_in, const int* in_sizes, int n_in,
                              void* d_out, int out_size, void* d_ws, size_t ws_size,
                              hipStream_t stream) {
    const float* feat    = (const float*)d_in[0];
    const float* anchors = (const float*)d_in[1];
    const float* wcls    = (const float*)d_in[2];
    const float* wloc    = (const float*)d_in[3];
    const int*   stridep = (const int*)d_in[4];
    float* out = (float*)d_out;
    float* ws  = (float*)d_ws;

    const size_t P1 = (size_t)NB * NPOS * OC_TOTAL;   // 737280 floats
    const size_t WTN = 3 * 256 * 144;                 // 110592 floats
    int nkg = 4;
    size_t need = (P1 * 4 + (size_t)NB * NANCH * 5 + WTN + 1024) * 4;
    if (ws_size < need) nkg = 1;

    float* partial = ws;
    float* boxes   = partial + P1 * nkg;
    float* scores  = boxes + (size_t)NB * NANCH * 4;
    float* wT      = scores + (size_t)NB * NANCH;
    int*   ifb     = (int*)(wT + WTN);
    int*   iok     = ifb + 512;

    wtrans_kernel<<<432, 256, 0, stream>>>(wcls, wloc, wT);
    conv_kernel<<<64 * 3 * nkg, 256, 0, stream>>>(feat, wT, partial, nkg, CIN / nkg);
    decode_kernel<<<(NB * NANCH) / 256, 256, 0, stream>>>(partial, anchors, stridep, boxes, scores, nkg);
    nms_kernel<<<NB, 1024, 0, stream>>>(boxes, scores, stridep, out, ifb, iok);
    roi_kernel<<<(NB * MAXROIS * CIN * 49) / 256, 256, 0, stream>>>(feat, ifb, iok, out + NB * MAXROIS * 5 + NB * MAXROIS);
}